// Round 7
// baseline (189.806 us; speedup 1.0000x reference)
//
#include <hip/hip_runtime.h>
#include <math.h>

#define N_NODES 50000
#define KNEI    32
#define DIM     128
#define DOUT    128
#define NUNITS  (2 * N_NODES)          // (node,list) units

#define GP1_BLOCKS 391                 // ceil(N/128) gemm-part1 blocks
#define AGG_BLOCKS (NUNITS / 32)       // 3125 aggregate blocks (exact)

typedef __attribute__((ext_vector_type(8))) short short8;
typedef __attribute__((ext_vector_type(4))) float floatx4;

// round-to-nearest-even fp32 -> bf16
static __device__ __forceinline__ unsigned short f2bf(float f) {
    unsigned int u = __float_as_uint(f);
    unsigned int lsb = (u >> 16) & 1u;
    u += 0x7fffu + lsb;
    return (unsigned short)(u >> 16);
}
static __device__ __forceinline__ unsigned int pack2(float a, float b) {
    return (unsigned int)f2bf(a) | ((unsigned int)f2bf(b) << 16);
}
// overflow-safe fast tanh: 1 - 2/(e^{2|x|}+1), sign-restored
static __device__ __forceinline__ float fast_tanh(float x) {
    float ax = fabsf(x);
    float e  = __expf(2.0f * ax);
    float t  = 1.0f - 2.0f / (e + 1.0f);
    return copysignf(t, x);
}
// biased-unsigned quantization: q = round(x*inv)+128 in [1,255]
static __device__ __forceinline__ unsigned int pk4_u8(float a, float b, float c,
                                                      float d, float inv) {
    int qa = ((int)rintf(a * inv) + 128) & 0xff;
    int qb = ((int)rintf(b * inv) + 128) & 0xff;
    int qc = ((int)rintf(c * inv) + 128) & 0xff;
    int qd = ((int)rintf(d * inv) + 128) & 0xff;
    return (unsigned int)(qa | (qb << 8) | (qc << 16) | (qd << 24));
}

// ---------------- fast path kernels ----------------

// blocks [0,1563): fea1 fp32 [N,128] -> biased-u8 Q8[N][128] + scale Sc[N]
// blocks [1563,1819): W fp32 [512,128] -> Wt bf16 [128][512]
__global__ __launch_bounds__(256) void convert_both(
    const float* __restrict__ fea1, const float* __restrict__ W,
    unsigned int* __restrict__ Q8, float* __restrict__ Sc,
    unsigned short* __restrict__ Wt)
{
    int b = blockIdx.x;
    if (b >= 1563) {
        int t = (b - 1563) * 256 + threadIdx.x;   // 0..65535
        int k = t >> 7, n = t & 127;
        Wt[n * 512 + k] = f2bf(W[t]);
        return;
    }
    int t = b * 256 + threadIdx.x;                // 0 .. N*8-1
    if (t >= N_NODES * 8) return;
    int node = t >> 3, j = t & 7;
    const float* rp = fea1 + node * DIM + j * 16;
    float4 v0 = *(const float4*)rp;
    float4 v1 = *(const float4*)(rp + 4);
    float4 v2 = *(const float4*)(rp + 8);
    float4 v3 = *(const float4*)(rp + 12);

    float am = fabsf(v0.x);
    am = fmaxf(am, fabsf(v0.y)); am = fmaxf(am, fabsf(v0.z)); am = fmaxf(am, fabsf(v0.w));
    am = fmaxf(am, fabsf(v1.x)); am = fmaxf(am, fabsf(v1.y));
    am = fmaxf(am, fabsf(v1.z)); am = fmaxf(am, fabsf(v1.w));
    am = fmaxf(am, fabsf(v2.x)); am = fmaxf(am, fabsf(v2.y));
    am = fmaxf(am, fabsf(v2.z)); am = fmaxf(am, fabsf(v2.w));
    am = fmaxf(am, fabsf(v3.x)); am = fmaxf(am, fabsf(v3.y));
    am = fmaxf(am, fabsf(v3.z)); am = fmaxf(am, fabsf(v3.w));
    // reduce absmax across the node's 8 threads (aligned group within a wave)
    #pragma unroll
    for (int d = 1; d < 8; d <<= 1) am = fmaxf(am, __shfl_xor(am, d, 64));

    float inv = (am > 1e-30f) ? 127.0f / am : 0.0f;
    int4 o;
    o.x = (int)pk4_u8(v0.x, v0.y, v0.z, v0.w, inv);
    o.y = (int)pk4_u8(v1.x, v1.y, v1.z, v1.w, inv);
    o.z = (int)pk4_u8(v2.x, v2.y, v2.z, v2.w, inv);
    o.w = (int)pk4_u8(v3.x, v3.y, v3.z, v3.w, inv);
    *(int4*)(Q8 + node * 32 + j * 4) = o;
    if (j == 0) Sc[node] = am * (1.0f / 127.0f);
}

// K2: co-scheduled kernel.
//  blocks [0, GP1_BLOCKS):     gemm part-1: K=0..255 (fea1|fea2) -> fp32 partial
//  blocks [GP1_BLOCKS, +3125): aggregate (exact r2 structure, 45us known-good)
// Rationale: agg is MSHR/latency-bound (HBM 2.2/6.3 TB/s, MFMA 0, occupancy-
// insensitive r2/r6); gemm-p1 has no dependency on NEI, so its MFMA/LDS work
// hides under the gather latency shadow (m114: separate pipes co-schedule).
__global__ __launch_bounds__(256) void agg_or_gemmp1(
    const float*          __restrict__ fea1,
    const float*          __restrict__ fea2,
    const unsigned char*  __restrict__ Q8,
    const float*          __restrict__ Sc,
    const int*            __restrict__ idx1,
    const int*            __restrict__ idx2,
    const unsigned short* __restrict__ Wt,    // [128][512] bf16
    unsigned short*       __restrict__ NEI,   // [N][256] bf16
    float*                __restrict__ part)  // [N][128] fp32 partial
{
    __shared__ unsigned char smem[36864];     // union: gemm As+Bs / agg idxs+scs
    const int tid = threadIdx.x;

    if (blockIdx.x < GP1_BLOCKS) {
        // ---------------- gemm part-1 ----------------
        unsigned short (*As)[72] = (unsigned short(*)[72])smem;
        unsigned short (*Bs)[72] = (unsigned short(*)[72])(smem + 18432);

        const int w    = tid >> 6;
        const int lane = tid & 63;
        const int m0   = blockIdx.x * 128;
        const int wm   = (w & 1) * 64;
        const int wn   = (w >> 1) * 64;
        const int lm   = lane & 15;
        const int lk   = (lane >> 4) * 8;

        floatx4 acc[4][4];
        #pragma unroll
        for (int i = 0; i < 4; ++i)
            #pragma unroll
            for (int j = 0; j < 4; ++j)
                acc[i][j] = (floatx4){0.f, 0.f, 0.f, 0.f};

        for (int cc = 0; cc < 4; ++cc) {
            const int kb = cc * 64;
            const float* src = (cc < 2) ? fea1 : fea2;
            const int cbase = (cc & 1) * 64;
            #pragma unroll
            for (int i = 0; i < 8; ++i) {
                int f   = tid + i * 256;      // 0..2047 float4 slots
                int row = f >> 4;
                int c4  = (f & 15) * 4;
                int node = m0 + row;
                if (node >= N_NODES) node = N_NODES - 1;
                float4 v = *(const float4*)(src + node * DIM + cbase + c4);
                *(unsigned int*)&As[row][c4 + 0] = pack2(v.x, v.y);
                *(unsigned int*)&As[row][c4 + 2] = pack2(v.z, v.w);
            }
            #pragma unroll
            for (int i = 0; i < 4; ++i) {
                int sl  = tid + i * 256;
                int row = sl >> 3;
                int o8  = (sl & 7) * 8;
                *(int4*)&Bs[row][o8] = *(const int4*)(Wt + row * 512 + kb + o8);
            }
            __syncthreads();

            #pragma unroll
            for (int ks = 0; ks < 64; ks += 32) {
                short8 af[4], bf_[4];
                #pragma unroll
                for (int im = 0; im < 4; ++im)
                    af[im] = *(const short8*)&As[wm + im * 16 + lm][ks + lk];
                #pragma unroll
                for (int in = 0; in < 4; ++in)
                    bf_[in] = *(const short8*)&Bs[wn + in * 16 + lm][ks + lk];
                #pragma unroll
                for (int im = 0; im < 4; ++im)
                    #pragma unroll
                    for (int in = 0; in < 4; ++in)
                        acc[im][in] = __builtin_amdgcn_mfma_f32_16x16x32_bf16(
                            af[im], bf_[in], acc[im][in], 0, 0, 0);
            }
            __syncthreads();
        }

        // store fp32 partials (C/D: col=lane&15, row=(lane>>4)*4+reg)
        #pragma unroll
        for (int im = 0; im < 4; ++im) {
            int rbase = m0 + wm + im * 16 + (lane >> 4) * 4;
            #pragma unroll
            for (int in = 0; in < 4; ++in) {
                int col = wn + in * 16 + lm;
                #pragma unroll
                for (int r = 0; r < 4; ++r) {
                    int node = rbase + r;
                    if (node < N_NODES)
                        part[node * DOUT + col] = acc[im][in][r];
                }
            }
        }
        return;
    }

    // ---------------- aggregate (exact r2 structure) ----------------
    int (*idxs)[40]  = (int(*)[40])smem;              // 5120 B
    float (*scs)[40] = (float(*)[40])(smem + 5120);   // 5120 B

    const int bu0 = (blockIdx.x - GP1_BLOCKS) * 32;   // first unit of block
    const int ul  = tid >> 3;                         // unit-in-block 0..31
    const int l   = tid & 7;                          // 16B chunk / scale quarter

    {
        int uu = bu0 + ul;                            // 3125*32 == NUNITS exactly
        const int* ip = ((uu & 1) ? idx2 : idx1) + (uu >> 1) * KNEI + l * 4;
        int4 v = *(const int4*)ip;
        *(int4*)&idxs[ul][l * 4] = v;
    }
    __syncthreads();
    {
        #pragma unroll
        for (int k = 0; k < 4; ++k)
            scs[ul][l * 4 + k] = Sc[idxs[ul][l * 4 + k]];
    }
    __syncthreads();

    const int u    = bu0 + ul;
    const int node = u >> 1;
    const int list = u & 1;

    const unsigned char* base = Q8 + l * 16;
    float sums[16];
    #pragma unroll
    for (int i = 0; i < 16; ++i) sums[i] = 0.f;
    float ssum = 0.f;                                 // sum of all 32 scales

    #pragma unroll 2
    for (int b = 0; b < 4; ++b) {
        int4 i4a = *(const int4*)&idxs[ul][b * 8];
        int4 i4b = *(const int4*)&idxs[ul][b * 8 + 4];
        int rows[8] = {i4a.x, i4a.y, i4a.z, i4a.w,
                       i4b.x, i4b.y, i4b.z, i4b.w};
        uint4 v[8];
        #pragma unroll
        for (int j = 0; j < 8; ++j)
            v[j] = *(const uint4*)(base + (size_t)rows[j] * 128);

        float4 sA = *(const float4*)&scs[ul][b * 8];
        float4 sB = *(const float4*)&scs[ul][b * 8 + 4];
        float sc8[8] = {sA.x, sA.y, sA.z, sA.w, sB.x, sB.y, sB.z, sB.w};
        ssum += sA.x + sA.y + sA.z + sA.w + sB.x + sB.y + sB.z + sB.w;

        #pragma unroll
        for (int j = 0; j < 8; ++j) {
            float s = sc8[j];
            unsigned int d0 = v[j].x, d1 = v[j].y, d2 = v[j].z, d3 = v[j].w;
            sums[0]  = fmaf(s, (float)(d0 & 0xffu),         sums[0]);
            sums[1]  = fmaf(s, (float)((d0 >> 8) & 0xffu),  sums[1]);
            sums[2]  = fmaf(s, (float)((d0 >> 16) & 0xffu), sums[2]);
            sums[3]  = fmaf(s, (float)(d0 >> 24),           sums[3]);
            sums[4]  = fmaf(s, (float)(d1 & 0xffu),         sums[4]);
            sums[5]  = fmaf(s, (float)((d1 >> 8) & 0xffu),  sums[5]);
            sums[6]  = fmaf(s, (float)((d1 >> 16) & 0xffu), sums[6]);
            sums[7]  = fmaf(s, (float)(d1 >> 24),           sums[7]);
            sums[8]  = fmaf(s, (float)(d2 & 0xffu),         sums[8]);
            sums[9]  = fmaf(s, (float)((d2 >> 8) & 0xffu),  sums[9]);
            sums[10] = fmaf(s, (float)((d2 >> 16) & 0xffu), sums[10]);
            sums[11] = fmaf(s, (float)(d2 >> 24),           sums[11]);
            sums[12] = fmaf(s, (float)(d3 & 0xffu),         sums[12]);
            sums[13] = fmaf(s, (float)((d3 >> 8) & 0xffu),  sums[13]);
            sums[14] = fmaf(s, (float)((d3 >> 16) & 0xffu), sums[14]);
            sums[15] = fmaf(s, (float)(d3 >> 24),           sums[15]);
        }
    }

    const float invK = 1.0f / 32.0f;
    const float corr = 128.0f * ssum;
    #pragma unroll
    for (int i = 0; i < 16; ++i) sums[i] = (sums[i] - corr) * invK;

    int4 o0, o1;
    o0.x = (int)pack2(sums[0],  sums[1]);
    o0.y = (int)pack2(sums[2],  sums[3]);
    o0.z = (int)pack2(sums[4],  sums[5]);
    o0.w = (int)pack2(sums[6],  sums[7]);
    o1.x = (int)pack2(sums[8],  sums[9]);
    o1.y = (int)pack2(sums[10], sums[11]);
    o1.z = (int)pack2(sums[12], sums[13]);
    o1.w = (int)pack2(sums[14], sums[15]);
    unsigned short* op = NEI + node * 256 + list * 128 + l * 16;
    *(int4*)op       = o0;
    *(int4*)(op + 8) = o1;
}

// K3: gemm part-2: K=256..511 from NEI, add fp32 partial, tanh, store.
__global__ __launch_bounds__(256) void gemm_p2(
    const unsigned short* __restrict__ NEI,   // [N][256] bf16
    const unsigned short* __restrict__ Wt,    // [128][512] bf16
    const float*          __restrict__ part,  // [N][128] fp32
    float* __restrict__ out)
{
    __shared__ unsigned short As[128][72];   // 18432 B
    __shared__ unsigned short Bs[128][72];   // 18432 B

    const int tid  = threadIdx.x;
    const int w    = tid >> 6;
    const int lane = tid & 63;
    const int m0   = blockIdx.x * 128;
    const int wm   = (w & 1) * 64;
    const int wn   = (w >> 1) * 64;
    const int lm   = lane & 15;
    const int lk   = (lane >> 4) * 8;

    floatx4 acc[4][4];
    #pragma unroll
    for (int i = 0; i < 4; ++i)
        #pragma unroll
        for (int j = 0; j < 4; ++j)
            acc[i][j] = (floatx4){0.f, 0.f, 0.f, 0.f};

    for (int cc = 0; cc < 4; ++cc) {
        const int kb = 256 + cc * 64;        // Wt k-range 256..511
        const int cb = cc * 64;              // NEI col-range 0..255
        #pragma unroll
        for (int i = 0; i < 4; ++i) {
            int sl  = tid + i * 256;         // 1024 int4 slots
            int row = sl >> 3;
            int o8  = (sl & 7) * 8;
            int node = m0 + row;
            if (node >= N_NODES) node = N_NODES - 1;
            *(int4*)&As[row][o8] = *(const int4*)(NEI + node * 256 + cb + o8);
        }
        #pragma unroll
        for (int i = 0; i < 4; ++i) {
            int sl  = tid + i * 256;
            int row = sl >> 3;
            int o8  = (sl & 7) * 8;
            *(int4*)&Bs[row][o8] = *(const int4*)(Wt + row * 512 + kb + o8);
        }
        __syncthreads();

        #pragma unroll
        for (int ks = 0; ks < 64; ks += 32) {
            short8 af[4], bf_[4];
            #pragma unroll
            for (int im = 0; im < 4; ++im)
                af[im] = *(const short8*)&As[wm + im * 16 + lm][ks + lk];
            #pragma unroll
            for (int in = 0; in < 4; ++in)
                bf_[in] = *(const short8*)&Bs[wn + in * 16 + lm][ks + lk];
            #pragma unroll
            for (int im = 0; im < 4; ++im)
                #pragma unroll
                for (int in = 0; in < 4; ++in)
                    acc[im][in] = __builtin_amdgcn_mfma_f32_16x16x32_bf16(
                        af[im], bf_[in], acc[im][in], 0, 0, 0);
        }
        __syncthreads();
    }

    // epilogue: out = tanh(acc + partial)
    #pragma unroll
    for (int im = 0; im < 4; ++im) {
        int rbase = m0 + wm + im * 16 + (lane >> 4) * 4;
        #pragma unroll
        for (int in = 0; in < 4; ++in) {
            int col = wn + in * 16 + lm;
            #pragma unroll
            for (int r = 0; r < 4; ++r) {
                int node = rbase + r;
                if (node < N_NODES)
                    out[node * DOUT + col] =
                        fast_tanh(acc[im][in][r] + part[node * DOUT + col]);
            }
        }
    }
}

// ---------------- fallback (ws too small): round-1 fused fp32 ----------------
#define MT      64
#define KC      64
#define AS_STRIDE 68

__global__ __launch_bounds__(256) void sage_fused_fb(
    const float* __restrict__ fea1, const float* __restrict__ fea2,
    const int* __restrict__ idx1, const int* __restrict__ idx2,
    const float* __restrict__ W, float* __restrict__ out)
{
    __shared__ float As[KC][AS_STRIDE];
    __shared__ int   idxs[MT][64];
    const int tid = threadIdx.x;
    const int n0  = blockIdx.x * MT;
    #pragma unroll
    for (int i = 0; i < 8; ++i) {
        int e = tid + i * 256, m = e >> 5, kk = e & 31;
        int node = n0 + m; if (node >= N_NODES) node = N_NODES - 1;
        idxs[m][kk]      = idx1[node * KNEI + kk];
        idxs[m][32 + kk] = idx2[node * KNEI + kk];
    }
    float acc[8][4];
    #pragma unroll
    for (int i = 0; i < 8; ++i)
        #pragma unroll
        for (int j = 0; j < 4; ++j) acc[i][j] = 0.f;
    const int j0 = (tid & 31) * 4;
    const int m0 = (tid >> 5) * 8;
    for (int c = 0; c < 8; ++c) {
        if (c < 4) {
            const float* src = (c < 2) ? fea1 : fea2;
            const int cbase = (c & 1) * 64;
            #pragma unroll
            for (int i = 0; i < 4; ++i) {
                int f = tid + i * 256, m = f >> 4, c4 = (f & 15) * 4;
                int node = n0 + m; if (node >= N_NODES) node = N_NODES - 1;
                float4 v = *(const float4*)(src + node * DIM + cbase + c4);
                As[c4 + 0][m] = v.x; As[c4 + 1][m] = v.y;
                As[c4 + 2][m] = v.z; As[c4 + 3][m] = v.w;
            }
        } else {
            const int col = tid & 63, kbase = (c & 1) * 64;
            const int lbase = (c < 6) ? 0 : 32, g = tid >> 6;
            for (int mm = 0; mm < 16; ++mm) {
                const int m = g * 16 + mm;
                const int4* ip = (const int4*)&idxs[m][lbase];
                float s = 0.f;
                #pragma unroll
                for (int q = 0; q < 8; ++q) {
                    int4 nb = ip[q];
                    s += fea1[nb.x * DIM + kbase + col];
                    s += fea1[nb.y * DIM + kbase + col];
                    s += fea1[nb.z * DIM + kbase + col];
                    s += fea1[nb.w * DIM + kbase + col];
                }
                As[col][m] = s * (1.0f / 32.0f);
            }
        }
        __syncthreads();
        const float* wp = W + (c * KC) * DOUT + j0;
        #pragma unroll 4
        for (int k = 0; k < KC; ++k) {
            float4 w4 = *(const float4*)(wp + k * DOUT);
            const float4* ap = (const float4*)&As[k][m0];
            float4 a0 = ap[0]; float4 a1 = ap[1];
            float av[8] = {a0.x, a0.y, a0.z, a0.w, a1.x, a1.y, a1.z, a1.w};
            #pragma unroll
            for (int i = 0; i < 8; ++i) {
                acc[i][0] += av[i] * w4.x; acc[i][1] += av[i] * w4.y;
                acc[i][2] += av[i] * w4.z; acc[i][3] += av[i] * w4.w;
            }
        }
        __syncthreads();
    }
    #pragma unroll
    for (int i = 0; i < 8; ++i) {
        int node = n0 + m0 + i;
        if (node < N_NODES) {
            float4 r;
            r.x = tanhf(acc[i][0]); r.y = tanhf(acc[i][1]);
            r.z = tanhf(acc[i][2]); r.w = tanhf(acc[i][3]);
            *(float4*)(out + node * DOUT + j0) = r;
        }
    }
}

extern "C" void kernel_launch(void* const* d_in, const int* in_sizes, int n_in,
                              void* d_out, int out_size, void* d_ws, size_t ws_size,
                              hipStream_t stream) {
    const float* fea1 = (const float*)d_in[0];
    const float* fea2 = (const float*)d_in[1];
    const int*   idx1 = (const int*)d_in[2];
    const int*   idx2 = (const int*)d_in[3];
    const float* W    = (const float*)d_in[4];
    float* out = (float*)d_out;

    const size_t Q8_BYTES   = (size_t)N_NODES * DIM;            //  6,400,000
    const size_t SC_BYTES   = (size_t)N_NODES * 4;              //    200,000
    const size_t NEI_BYTES  = (size_t)N_NODES * 256 * 2;        // 25,600,000
    const size_t WT_BYTES   = (size_t)512 * 128 * 2;            //    131,072
    const size_t PART_BYTES = (size_t)N_NODES * DOUT * 4;       // 25,600,000

    if (ws_size >= Q8_BYTES + SC_BYTES + NEI_BYTES + WT_BYTES + PART_BYTES) {
        unsigned char*  Q8  = (unsigned char*)d_ws;
        float*          Scp = (float*)((char*)d_ws + Q8_BYTES);
        unsigned short* NEI = (unsigned short*)((char*)d_ws + Q8_BYTES + SC_BYTES);
        unsigned short* Wt  = (unsigned short*)((char*)d_ws + Q8_BYTES + SC_BYTES + NEI_BYTES);
        float*          Pp  = (float*)((char*)d_ws + Q8_BYTES + SC_BYTES + NEI_BYTES + WT_BYTES);

        convert_both<<<1563 + 256, 256, 0, stream>>>(
            fea1, W, (unsigned int*)Q8, Scp, Wt);
        agg_or_gemmp1<<<GP1_BLOCKS + AGG_BLOCKS, 256, 0, stream>>>(
            fea1, fea2, Q8, Scp, idx1, idx2, Wt, NEI, Pp);
        gemm_p2<<<GP1_BLOCKS, 256, 0, stream>>>(NEI, Wt, Pp, out);
    } else {
        const int grid = (N_NODES + MT - 1) / MT;
        sage_fused_fb<<<grid, 256, 0, stream>>>(fea1, fea2, idx1, idx2, W, out);
    }
}

// Round 8
// 163.533 us; speedup vs baseline: 1.1607x; 1.1607x over previous
//
#include <hip/hip_runtime.h>
#include <math.h>

#define N_NODES 50000
#define KNEI    32
#define DIM     128
#define DOUT    128
#define NUNITS  (2 * N_NODES)          // (node,list) units

typedef __attribute__((ext_vector_type(8))) short short8;
typedef __attribute__((ext_vector_type(4))) float floatx4;

// round-to-nearest-even fp32 -> bf16
static __device__ __forceinline__ unsigned short f2bf(float f) {
    unsigned int u = __float_as_uint(f);
    unsigned int lsb = (u >> 16) & 1u;
    u += 0x7fffu + lsb;
    return (unsigned short)(u >> 16);
}
static __device__ __forceinline__ unsigned int pack2(float a, float b) {
    return (unsigned int)f2bf(a) | ((unsigned int)f2bf(b) << 16);
}
// overflow-safe fast tanh: 1 - 2/(e^{2|x|}+1), sign-restored
static __device__ __forceinline__ float fast_tanh(float x) {
    float ax = fabsf(x);
    float e  = __expf(2.0f * ax);
    float t  = 1.0f - 2.0f / (e + 1.0f);
    return copysignf(t, x);
}
// biased-unsigned quantization: q = round(x*inv)+128 in [1,255]
static __device__ __forceinline__ unsigned int pk4_u8(float a, float b, float c,
                                                      float d, float inv) {
    int qa = ((int)rintf(a * inv) + 128) & 0xff;
    int qb = ((int)rintf(b * inv) + 128) & 0xff;
    int qc = ((int)rintf(c * inv) + 128) & 0xff;
    int qd = ((int)rintf(d * inv) + 128) & 0xff;
    return (unsigned int)(qa | (qb << 8) | (qc << 16) | (qd << 24));
}

// ---------------- fast path kernels ----------------

// blocks [0,1563): fea1 fp32 [N,128] -> biased-u8 Q8[N][128] + scale Sc[N]
// blocks [1563,1819): W fp32 [512,128] -> Wt bf16 [128][512]
__global__ __launch_bounds__(256) void convert_both(
    const float* __restrict__ fea1, const float* __restrict__ W,
    unsigned int* __restrict__ Q8, float* __restrict__ Sc,
    unsigned short* __restrict__ Wt)
{
    int b = blockIdx.x;
    if (b >= 1563) {
        int t = (b - 1563) * 256 + threadIdx.x;   // 0..65535
        int k = t >> 7, n = t & 127;
        Wt[n * 512 + k] = f2bf(W[t]);
        return;
    }
    int t = b * 256 + threadIdx.x;                // 0 .. N*8-1
    if (t >= N_NODES * 8) return;
    int node = t >> 3, j = t & 7;
    const float* rp = fea1 + node * DIM + j * 16;
    float4 v0 = *(const float4*)rp;
    float4 v1 = *(const float4*)(rp + 4);
    float4 v2 = *(const float4*)(rp + 8);
    float4 v3 = *(const float4*)(rp + 12);

    float am = fabsf(v0.x);
    am = fmaxf(am, fabsf(v0.y)); am = fmaxf(am, fabsf(v0.z)); am = fmaxf(am, fabsf(v0.w));
    am = fmaxf(am, fabsf(v1.x)); am = fmaxf(am, fabsf(v1.y));
    am = fmaxf(am, fabsf(v1.z)); am = fmaxf(am, fabsf(v1.w));
    am = fmaxf(am, fabsf(v2.x)); am = fmaxf(am, fabsf(v2.y));
    am = fmaxf(am, fabsf(v2.z)); am = fmaxf(am, fabsf(v2.w));
    am = fmaxf(am, fabsf(v3.x)); am = fmaxf(am, fabsf(v3.y));
    am = fmaxf(am, fabsf(v3.z)); am = fmaxf(am, fabsf(v3.w));
    // reduce absmax across the node's 8 threads (aligned group within a wave)
    #pragma unroll
    for (int d = 1; d < 8; d <<= 1) am = fmaxf(am, __shfl_xor(am, d, 64));

    float inv = (am > 1e-30f) ? 127.0f / am : 0.0f;
    int4 o;
    o.x = (int)pk4_u8(v0.x, v0.y, v0.z, v0.w, inv);
    o.y = (int)pk4_u8(v1.x, v1.y, v1.z, v1.w, inv);
    o.z = (int)pk4_u8(v2.x, v2.y, v2.z, v2.w, inv);
    o.w = (int)pk4_u8(v3.x, v3.y, v3.z, v3.w, inv);
    *(int4*)(Q8 + node * 32 + j * 4) = o;
    if (j == 0) Sc[node] = am * (1.0f / 127.0f);
}

// gather-mean over biased-u8 table with per-row scale (r2 structure verbatim —
// best measured: 45us, 40 VGPR, 46% occ). 8 lanes/unit (16B chunk of 128B row),
// 32 units per 256-thread block; indices+scales staged in LDS.
// Probed and rejected: deeper ILP (r1: spills), 64-VGPR cap (r1), column-plane
// L2-split (r5: line-touches double), 1024-thr blocks (r6), co-scheduled GEMM
// (r7: register-union kills agg occupancy). This is the latency/overlap floor
// for this gather pattern.
__global__ __launch_bounds__(256) void aggregate_i8(
    const unsigned char* __restrict__ Q8,
    const float* __restrict__ Sc,
    const int* __restrict__ idx1,
    const int* __restrict__ idx2,
    unsigned short* __restrict__ NEI)
{
    __shared__ int   idxs[32][40];   // stride 40: 16B-aligned rows, 2-way banks
    __shared__ float scs[32][40];

    const int tid = threadIdx.x;
    const int bu0 = blockIdx.x * 32;            // first unit of block
    const int ul  = tid >> 3;                   // unit-in-block 0..31
    const int l   = tid & 7;                    // 16B chunk / scale quarter

    // ---- stage indices: 32 units x 32 ints, 1 int4/thread ----
    {
        int uu = bu0 + ul;                      // 3125*32 == NUNITS exactly
        const int* ip = ((uu & 1) ? idx2 : idx1) + (uu >> 1) * KNEI + l * 4;
        int4 v = *(const int4*)ip;
        *(int4*)&idxs[ul][l * 4] = v;
    }
    __syncthreads();

    // ---- stage scales: lane l gathers 4 of its unit's 32 ----
    {
        #pragma unroll
        for (int k = 0; k < 4; ++k)
            scs[ul][l * 4 + k] = Sc[idxs[ul][l * 4 + k]];
    }
    __syncthreads();

    const int u    = bu0 + ul;
    const int node = u >> 1;
    const int list = u & 1;

    const unsigned char* base = Q8 + l * 16;
    float sums[16];
    #pragma unroll
    for (int i = 0; i < 16; ++i) sums[i] = 0.f;
    float ssum = 0.f;                            // sum of all 32 scales

    #pragma unroll 2
    for (int b = 0; b < 4; ++b) {
        // batch of 8 rows: issue all 8 gathers before any unpack
        int4 i4a = *(const int4*)&idxs[ul][b * 8];
        int4 i4b = *(const int4*)&idxs[ul][b * 8 + 4];
        int rows[8] = {i4a.x, i4a.y, i4a.z, i4a.w,
                       i4b.x, i4b.y, i4b.z, i4b.w};
        uint4 v[8];
        #pragma unroll
        for (int j = 0; j < 8; ++j)
            v[j] = *(const uint4*)(base + (size_t)rows[j] * 128);

        float4 sA = *(const float4*)&scs[ul][b * 8];
        float4 sB = *(const float4*)&scs[ul][b * 8 + 4];
        float sc8[8] = {sA.x, sA.y, sA.z, sA.w, sB.x, sB.y, sB.z, sB.w};
        ssum += sA.x + sA.y + sA.z + sA.w + sB.x + sB.y + sB.z + sB.w;

        #pragma unroll
        for (int j = 0; j < 8; ++j) {
            float s = sc8[j];
            unsigned int d0 = v[j].x, d1 = v[j].y, d2 = v[j].z, d3 = v[j].w;
            sums[0]  = fmaf(s, (float)(d0 & 0xffu),         sums[0]);
            sums[1]  = fmaf(s, (float)((d0 >> 8) & 0xffu),  sums[1]);
            sums[2]  = fmaf(s, (float)((d0 >> 16) & 0xffu), sums[2]);
            sums[3]  = fmaf(s, (float)(d0 >> 24),           sums[3]);
            sums[4]  = fmaf(s, (float)(d1 & 0xffu),         sums[4]);
            sums[5]  = fmaf(s, (float)((d1 >> 8) & 0xffu),  sums[5]);
            sums[6]  = fmaf(s, (float)((d1 >> 16) & 0xffu), sums[6]);
            sums[7]  = fmaf(s, (float)(d1 >> 24),           sums[7]);
            sums[8]  = fmaf(s, (float)(d2 & 0xffu),         sums[8]);
            sums[9]  = fmaf(s, (float)((d2 >> 8) & 0xffu),  sums[9]);
            sums[10] = fmaf(s, (float)((d2 >> 16) & 0xffu), sums[10]);
            sums[11] = fmaf(s, (float)(d2 >> 24),           sums[11]);
            sums[12] = fmaf(s, (float)(d3 & 0xffu),         sums[12]);
            sums[13] = fmaf(s, (float)((d3 >> 8) & 0xffu),  sums[13]);
            sums[14] = fmaf(s, (float)((d3 >> 16) & 0xffu), sums[14]);
            sums[15] = fmaf(s, (float)(d3 >> 24),           sums[15]);
        }
    }

    // remove the +128 bias: sum_c = sum s_k*u_k - 128*sum s_k, then mean
    const float invK = 1.0f / 32.0f;
    const float corr = 128.0f * ssum;
    #pragma unroll
    for (int i = 0; i < 16; ++i) sums[i] = (sums[i] - corr) * invK;

    int4 o0, o1;
    o0.x = (int)pack2(sums[0],  sums[1]);
    o0.y = (int)pack2(sums[2],  sums[3]);
    o0.z = (int)pack2(sums[4],  sums[5]);
    o0.w = (int)pack2(sums[6],  sums[7]);
    o1.x = (int)pack2(sums[8],  sums[9]);
    o1.y = (int)pack2(sums[10], sums[11]);
    o1.z = (int)pack2(sums[12], sums[13]);
    o1.w = (int)pack2(sums[14], sums[15]);
    unsigned short* op = NEI + node * 256 + list * 128 + l * 16;
    *(int4*)op       = o0;
    *(int4*)(op + 8) = o1;
}

// out = tanh([fea1|fea2|nei1|nei2] @ Wt^T); 128x128 tile, bf16 MFMA, fp32
// accum. (r0/r2 structure, best measured. Probed and rejected: M=32 (r1:
// 8x B restage), in-kernel agg fusion (r3: spills), K-split two-pass (r7).)
__global__ __launch_bounds__(256) void gemm128(
    const float*          __restrict__ fea1,
    const float*          __restrict__ fea2,
    const unsigned short* __restrict__ NEI,   // [N][256] bf16
    const unsigned short* __restrict__ Wt,    // [128][512] bf16
    float* __restrict__ out)
{
    __shared__ unsigned short As[128][72];   // 18432 B
    __shared__ unsigned short Bs[128][72];   // 18432 B

    const int tid  = threadIdx.x;
    const int w    = tid >> 6;
    const int lane = tid & 63;
    const int m0   = blockIdx.x * 128;
    const int wm   = (w & 1) * 64;
    const int wn   = (w >> 1) * 64;
    const int lm   = lane & 15;
    const int lk   = (lane >> 4) * 8;

    floatx4 acc[4][4];
    #pragma unroll
    for (int i = 0; i < 4; ++i)
        #pragma unroll
        for (int j = 0; j < 4; ++j)
            acc[i][j] = (floatx4){0.f, 0.f, 0.f, 0.f};

    for (int cc = 0; cc < 8; ++cc) {
        const int kb = cc * 64;
        // ---- stage A tile: 128 rows x 64 bf16 cols ----
        if (cc < 4) {
            const float* src = (cc < 2) ? fea1 : fea2;
            const int cbase = (cc & 1) * 64;
            #pragma unroll
            for (int i = 0; i < 8; ++i) {
                int f   = tid + i * 256;      // 0..2047 float4 slots
                int row = f >> 4;             // 16 float4 per 64-col chunk
                int c4  = (f & 15) * 4;
                int node = m0 + row;
                if (node >= N_NODES) node = N_NODES - 1;
                float4 v = *(const float4*)(src + node * DIM + cbase + c4);
                *(unsigned int*)&As[row][c4 + 0] = pack2(v.x, v.y);
                *(unsigned int*)&As[row][c4 + 2] = pack2(v.z, v.w);
            }
        } else {
            const int cb = kb - 256;
            #pragma unroll
            for (int i = 0; i < 4; ++i) {
                int sl  = tid + i * 256;      // 1024 int4 slots
                int row = sl >> 3;
                int o8  = (sl & 7) * 8;
                int node = m0 + row;
                if (node >= N_NODES) node = N_NODES - 1;
                *(int4*)&As[row][o8] = *(const int4*)(NEI + node * 256 + cb + o8);
            }
        }
        // ---- stage B tile: 128 out-cols x 64 k ----
        #pragma unroll
        for (int i = 0; i < 4; ++i) {
            int sl  = tid + i * 256;
            int row = sl >> 3;
            int o8  = (sl & 7) * 8;
            *(int4*)&Bs[row][o8] = *(const int4*)(Wt + row * 512 + kb + o8);
        }
        __syncthreads();

        #pragma unroll
        for (int ks = 0; ks < 64; ks += 32) {
            short8 af[4], bf_[4];
            #pragma unroll
            for (int im = 0; im < 4; ++im)
                af[im] = *(const short8*)&As[wm + im * 16 + lm][ks + lk];
            #pragma unroll
            for (int in = 0; in < 4; ++in)
                bf_[in] = *(const short8*)&Bs[wn + in * 16 + lm][ks + lk];
            #pragma unroll
            for (int im = 0; im < 4; ++im)
                #pragma unroll
                for (int in = 0; in < 4; ++in)
                    acc[im][in] = __builtin_amdgcn_mfma_f32_16x16x32_bf16(
                        af[im], bf_[in], acc[im][in], 0, 0, 0);
        }
        __syncthreads();
    }

    // epilogue (C/D: col=lane&15, row=(lane>>4)*4+reg) — layout verified
    #pragma unroll
    for (int im = 0; im < 4; ++im) {
        int rbase = m0 + wm + im * 16 + (lane >> 4) * 4;
        #pragma unroll
        for (int in = 0; in < 4; ++in) {
            int col = wn + in * 16 + lm;
            #pragma unroll
            for (int r = 0; r < 4; ++r) {
                int node = rbase + r;
                if (node < N_NODES)
                    out[node * DOUT + col] = fast_tanh(acc[im][in][r]);
            }
        }
    }
}

// ---------------- fallback (ws too small): round-1 fused fp32 ----------------
#define MT      64
#define KC      64
#define AS_STRIDE 68

__global__ __launch_bounds__(256) void sage_fused_fb(
    const float* __restrict__ fea1, const float* __restrict__ fea2,
    const int* __restrict__ idx1, const int* __restrict__ idx2,
    const float* __restrict__ W, float* __restrict__ out)
{
    __shared__ float As[KC][AS_STRIDE];
    __shared__ int   idxs[MT][64];
    const int tid = threadIdx.x;
    const int n0  = blockIdx.x * MT;
    #pragma unroll
    for (int i = 0; i < 8; ++i) {
        int e = tid + i * 256, m = e >> 5, kk = e & 31;
        int node = n0 + m; if (node >= N_NODES) node = N_NODES - 1;
        idxs[m][kk]      = idx1[node * KNEI + kk];
        idxs[m][32 + kk] = idx2[node * KNEI + kk];
    }
    float acc[8][4];
    #pragma unroll
    for (int i = 0; i < 8; ++i)
        #pragma unroll
        for (int j = 0; j < 4; ++j) acc[i][j] = 0.f;
    const int j0 = (tid & 31) * 4;
    const int m0 = (tid >> 5) * 8;
    for (int c = 0; c < 8; ++c) {
        if (c < 4) {
            const float* src = (c < 2) ? fea1 : fea2;
            const int cbase = (c & 1) * 64;
            #pragma unroll
            for (int i = 0; i < 4; ++i) {
                int f = tid + i * 256, m = f >> 4, c4 = (f & 15) * 4;
                int node = n0 + m; if (node >= N_NODES) node = N_NODES - 1;
                float4 v = *(const float4*)(src + node * DIM + cbase + c4);
                As[c4 + 0][m] = v.x; As[c4 + 1][m] = v.y;
                As[c4 + 2][m] = v.z; As[c4 + 3][m] = v.w;
            }
        } else {
            const int col = tid & 63, kbase = (c & 1) * 64;
            const int lbase = (c < 6) ? 0 : 32, g = tid >> 6;
            for (int mm = 0; mm < 16; ++mm) {
                const int m = g * 16 + mm;
                const int4* ip = (const int4*)&idxs[m][lbase];
                float s = 0.f;
                #pragma unroll
                for (int q = 0; q < 8; ++q) {
                    int4 nb = ip[q];
                    s += fea1[nb.x * DIM + kbase + col];
                    s += fea1[nb.y * DIM + kbase + col];
                    s += fea1[nb.z * DIM + kbase + col];
                    s += fea1[nb.w * DIM + kbase + col];
                }
                As[col][m] = s * (1.0f / 32.0f);
            }
        }
        __syncthreads();
        const float* wp = W + (c * KC) * DOUT + j0;
        #pragma unroll 4
        for (int k = 0; k < KC; ++k) {
            float4 w4 = *(const float4*)(wp + k * DOUT);
            const float4* ap = (const float4*)&As[k][m0];
            float4 a0 = ap[0]; float4 a1 = ap[1];
            float av[8] = {a0.x, a0.y, a0.z, a0.w, a1.x, a1.y, a1.z, a1.w};
            #pragma unroll
            for (int i = 0; i < 8; ++i) {
                acc[i][0] += av[i] * w4.x; acc[i][1] += av[i] * w4.y;
                acc[i][2] += av[i] * w4.z; acc[i][3] += av[i] * w4.w;
            }
        }
        __syncthreads();
    }
    #pragma unroll
    for (int i = 0; i < 8; ++i) {
        int node = n0 + m0 + i;
        if (node < N_NODES) {
            float4 r;
            r.x = tanhf(acc[i][0]); r.y = tanhf(acc[i][1]);
            r.z = tanhf(acc[i][2]); r.w = tanhf(acc[i][3]);
            *(float4*)(out + node * DOUT + j0) = r;
        }
    }
}

extern "C" void kernel_launch(void* const* d_in, const int* in_sizes, int n_in,
                              void* d_out, int out_size, void* d_ws, size_t ws_size,
                              hipStream_t stream) {
    const float* fea1 = (const float*)d_in[0];
    const float* fea2 = (const float*)d_in[1];
    const int*   idx1 = (const int*)d_in[2];
    const int*   idx2 = (const int*)d_in[3];
    const float* W    = (const float*)d_in[4];
    float* out = (float*)d_out;

    const size_t Q8_BYTES  = (size_t)N_NODES * DIM;            //  6,400,000
    const size_t SC_BYTES  = (size_t)N_NODES * 4;              //    200,000
    const size_t NEI_BYTES = (size_t)N_NODES * 256 * 2;        // 25,600,000
    const size_t WT_BYTES  = (size_t)512 * 128 * 2;            //    131,072

    if (ws_size >= Q8_BYTES + SC_BYTES + NEI_BYTES + WT_BYTES) {
        unsigned char*  Q8  = (unsigned char*)d_ws;
        float*          Scp = (float*)((char*)d_ws + Q8_BYTES);
        unsigned short* NEI = (unsigned short*)((char*)d_ws + Q8_BYTES + SC_BYTES);
        unsigned short* Wt  = (unsigned short*)((char*)d_ws + Q8_BYTES + SC_BYTES + NEI_BYTES);

        convert_both<<<1563 + 256, 256, 0, stream>>>(
            fea1, W, (unsigned int*)Q8, Scp, Wt);
        aggregate_i8<<<NUNITS / 32, 256, 0, stream>>>(Q8, Scp, idx1, idx2, NEI);
        gemm128<<<(N_NODES + 127) / 128, 256, 0, stream>>>(fea1, fea2, NEI, Wt, out);
    } else {
        const int grid = (N_NODES + MT - 1) / MT;
        sage_fused_fb<<<grid, 256, 0, stream>>>(fea1, fea2, idx1, idx2, W, out);
    }
}